// Round 1
// baseline (20.530 us; speedup 1.0000x reference)
//
#include <hip/hip_runtime.h>

// Problem constants (from reference):
//   B=16384 samples, IN=256 input dims, N=64 neurons, DEG=7 -> D = 256*8 = 2048
// Key identity: out[b] = sum_n hw[n] * (T[b] . c_n) = T[b] . (sum_n hw[n] c_n)
// so we precompute w[d] = sum_n coeffs[n][d]*hw[n] (2048 floats in d_ws), then
// each sample is: tanh -> Chebyshev T0..T7 per input dim -> 8-term dot -> block sum.

constexpr int B_SAMPLES = 16384;
constexpr int IN_DIM    = 256;
constexpr int N_NEURONS = 64;
constexpr int DEGP1     = 8;
constexpr int D_FEAT    = IN_DIM * DEGP1;  // 2048

// Kernel A: w[d] = sum_n coeffs[n*D + d] * hw[n]   (coalesced over d)
__global__ __launch_bounds__(256) void kan_reduce_w(const float* __restrict__ coeffs,
                                                    const float* __restrict__ hw,
                                                    float* __restrict__ w) {
    int d = blockIdx.x * 256 + threadIdx.x;
    if (d >= D_FEAT) return;
    float acc = 0.f;
#pragma unroll
    for (int n = 0; n < N_NEURONS; ++n)
        acc = fmaf(coeffs[n * D_FEAT + d], hw[n], acc);
    w[d] = acc;
}

// Kernel B: one block of 256 threads handles SPB samples; thread i owns input dim i.
constexpr int SPB = 16;  // samples per block -> grid = 1024 blocks

__global__ __launch_bounds__(256) void kan_fwd(const float* __restrict__ x,
                                               const float* __restrict__ w,
                                               float* __restrict__ out) {
    const int tid  = threadIdx.x;       // input dim
    const int lane = tid & 63;
    const int wave = tid >> 6;          // 0..3
    const int b0   = blockIdx.x * SPB;

    // Per-thread weight slice w[tid*8 .. tid*8+7] (loaded once per block).
    const float4 wlo = *reinterpret_cast<const float4*>(w + tid * DEGP1);
    const float4 whi = *reinterpret_cast<const float4*>(w + tid * DEGP1 + 4);

    __shared__ float red[SPB][4];

    for (int s = 0; s < SPB; ++s) {
        const int b = b0 + s;
        const float t = tanhf(x[(size_t)b * IN_DIM + tid]);  // coalesced 4B/lane

        // Chebyshev recurrence T0..T7, fused dot with w slice.
        const float t2 = 2.f * t;
        float Tm2 = 1.f, Tm1 = t;
        float acc = fmaf(wlo.y, t, wlo.x);           // w0*T0 + w1*T1
        float T;
        T = t2 * Tm1 - Tm2; acc = fmaf(wlo.z, T, acc); Tm2 = Tm1; Tm1 = T;  // T2
        T = t2 * Tm1 - Tm2; acc = fmaf(wlo.w, T, acc); Tm2 = Tm1; Tm1 = T;  // T3
        T = t2 * Tm1 - Tm2; acc = fmaf(whi.x, T, acc); Tm2 = Tm1; Tm1 = T;  // T4
        T = t2 * Tm1 - Tm2; acc = fmaf(whi.y, T, acc); Tm2 = Tm1; Tm1 = T;  // T5
        T = t2 * Tm1 - Tm2; acc = fmaf(whi.z, T, acc); Tm2 = Tm1; Tm1 = T;  // T6
        T = t2 * Tm1 - Tm2; acc = fmaf(whi.w, T, acc);                      // T7

        // wave-64 shuffle reduction
#pragma unroll
        for (int off = 32; off > 0; off >>= 1)
            acc += __shfl_down(acc, off, 64);
        if (lane == 0) red[s][wave] = acc;
    }
    __syncthreads();
    if (tid < SPB) {
        out[b0 + tid] = red[tid][0] + red[tid][1] + red[tid][2] + red[tid][3];
    }
}

extern "C" void kernel_launch(void* const* d_in, const int* in_sizes, int n_in,
                              void* d_out, int out_size, void* d_ws, size_t ws_size,
                              hipStream_t stream) {
    const float* x      = (const float*)d_in[0];   // [B, IN]
    const float* coeffs = (const float*)d_in[1];   // [N, D]
    const float* hw     = (const float*)d_in[2];   // [N]
    float* out = (float*)d_out;                    // [B] (B x 1)
    float* w   = (float*)d_ws;                     // 2048 floats scratch

    kan_reduce_w<<<(D_FEAT + 255) / 256, 256, 0, stream>>>(coeffs, hw, w);
    kan_fwd<<<B_SAMPLES / SPB, 256, 0, stream>>>(x, w, out);
}

// Round 2
// 17.286 us; speedup vs baseline: 1.1877x; 1.1877x over previous
//
#include <hip/hip_runtime.h>

// B=16384, IN=256, N=64, DEG=7 -> D = 2048
// Identity: out[b] = T[b] . (coeffs^T @ hw)  -- collapse neurons first.
// Kernel A: w[d] = sum_n coeffs[n][d]*hw[n]          (2048 floats in d_ws)
// Kernel B: per sample: tanh -> Cheb T0..T7 -> dot(w) -> wave-reduce -> out[b]

constexpr int B_SAMPLES = 16384;
constexpr int IN_DIM    = 256;
constexpr int N_NEURONS = 64;
constexpr int DEGP1     = 8;
constexpr int D_FEAT    = IN_DIM * DEGP1;  // 2048

__device__ __forceinline__ float fast_tanh(float v) {
    // tanh(v) = 1 - 2/(e^{2v}+1); exact limits: v>>0 -> e=inf -> 1; v<<0 -> e~0 -> -1.
    float e = __expf(2.0f * v);
    return 1.0f - 2.0f * __builtin_amdgcn_rcpf(e + 1.0f);
}

// ---- Kernel A: w = coeffs^T @ hw, float4-vectorized over d. 512 threads total.
__global__ __launch_bounds__(256) void kan_reduce_w(const float* __restrict__ coeffs,
                                                    const float* __restrict__ hw,
                                                    float* __restrict__ w) {
    int d4 = blockIdx.x * 256 + threadIdx.x;        // one float4 of w per thread
    if (d4 >= D_FEAT / 4) return;
    const float4* c4 = reinterpret_cast<const float4*>(coeffs);
    float4 acc = {0.f, 0.f, 0.f, 0.f};
#pragma unroll
    for (int n = 0; n < N_NEURONS; ++n) {
        float h = hw[n];
        float4 c = c4[n * (D_FEAT / 4) + d4];
        acc.x = fmaf(c.x, h, acc.x);
        acc.y = fmaf(c.y, h, acc.y);
        acc.z = fmaf(c.z, h, acc.z);
        acc.w = fmaf(c.w, h, acc.w);
    }
    reinterpret_cast<float4*>(w)[d4] = acc;
}

// ---- Kernel B: one wave per sample; lane handles 4 input dims (float4 load).
constexpr int SPB = 16;  // samples per 256-thread block (4 waves x 4 iters) -> 1024 blocks

__global__ __launch_bounds__(256) void kan_fwd(const float* __restrict__ x,
                                               const float* __restrict__ w,
                                               float* __restrict__ out) {
    const int tid  = threadIdx.x;
    const int lane = tid & 63;
    const int wv   = tid >> 6;                      // wave 0..3
    const int b0   = blockIdx.x * SPB;

    // Lane owns dims 4*lane .. 4*lane+3; weights w[d*8 .. d*8+7] -> 8 float4s.
    const float4* w4 = reinterpret_cast<const float4*>(w) + (size_t)lane * 8;
    float4 W[4][2];
#pragma unroll
    for (int j = 0; j < 4; ++j) { W[j][0] = w4[j * 2]; W[j][1] = w4[j * 2 + 1]; }

#pragma unroll
    for (int s = wv; s < SPB; s += 4) {
        const int b = b0 + s;
        float4 xv = reinterpret_cast<const float4*>(x + (size_t)b * IN_DIM)[lane];
        float xs[4] = {xv.x, xv.y, xv.z, xv.w};
        float acc = 0.f;
#pragma unroll
        for (int j = 0; j < 4; ++j) {
            const float t  = fast_tanh(xs[j]);
            const float t2 = 2.f * t;
            const float4 wlo = W[j][0], whi = W[j][1];
            float Tm2 = 1.f, Tm1 = t, T;
            float a = fmaf(wlo.y, t, wlo.x);                                    // T0,T1
            T = t2 * Tm1 - Tm2; a = fmaf(wlo.z, T, a); Tm2 = Tm1; Tm1 = T;      // T2
            T = t2 * Tm1 - Tm2; a = fmaf(wlo.w, T, a); Tm2 = Tm1; Tm1 = T;      // T3
            T = t2 * Tm1 - Tm2; a = fmaf(whi.x, T, a); Tm2 = Tm1; Tm1 = T;      // T4
            T = t2 * Tm1 - Tm2; a = fmaf(whi.y, T, a); Tm2 = Tm1; Tm1 = T;      // T5
            T = t2 * Tm1 - Tm2; a = fmaf(whi.z, T, a); Tm2 = Tm1; Tm1 = T;      // T6
            T = t2 * Tm1 - Tm2; a = fmaf(whi.w, T, a);                          // T7
            acc += a;
        }
        // wave-64 reduction, lane 0 stores the sample's output directly.
#pragma unroll
        for (int off = 32; off > 0; off >>= 1)
            acc += __shfl_down(acc, off, 64);
        if (lane == 0) out[b] = acc;
    }
}

extern "C" void kernel_launch(void* const* d_in, const int* in_sizes, int n_in,
                              void* d_out, int out_size, void* d_ws, size_t ws_size,
                              hipStream_t stream) {
    const float* x      = (const float*)d_in[0];   // [B, IN]
    const float* coeffs = (const float*)d_in[1];   // [N, D]
    const float* hw     = (const float*)d_in[2];   // [N]
    float* out = (float*)d_out;                    // [B]
    float* w   = (float*)d_ws;                     // 2048 floats scratch

    kan_reduce_w<<<(D_FEAT / 4 + 255) / 256, 256, 0, stream>>>(coeffs, hw, w);
    kan_fwd<<<B_SAMPLES / SPB, 256, 0, stream>>>(x, w, out);
}

// Round 3
// 16.844 us; speedup vs baseline: 1.2189x; 1.0263x over previous
//
#include <hip/hip_runtime.h>

// B=16384, IN=256, N=64, DEG=7 -> D = 2048
// Identity: out[b] = T[b] . (coeffs^T @ hw)  -- collapse neurons first.
// Kernel A: w[d] = sum_n coeffs[n][d]*hw[n]   (2048 floats in d_ws)
//           R2 lesson: 2-block version was latency/BW-starved (~10us on 2 CUs);
//           now 32 blocks x (16 d4-columns x 16 neuron-chunks) + LDS tree.
// Kernel B: per sample: tanh -> Cheb T0..T7 -> dot(w) -> wave-reduce -> out[b]

constexpr int B_SAMPLES = 16384;
constexpr int IN_DIM    = 256;
constexpr int N_NEURONS = 64;
constexpr int DEGP1     = 8;
constexpr int D_FEAT    = IN_DIM * DEGP1;  // 2048
constexpr int D4        = D_FEAT / 4;      // 512 float4 columns

__device__ __forceinline__ float fast_tanh(float v) {
    // tanh(v) = 1 - 2/(e^{2v}+1); exact limits at +/-inf.
    float e = __expf(2.0f * v);
    return 1.0f - 2.0f * __builtin_amdgcn_rcpf(e + 1.0f);
}

// ---- Kernel A: w = coeffs^T @ hw. 32 blocks; block owns 16 d4 columns.
// Thread (chunk, d4l) = (tid>>4, tid&15): partial over 4 neurons, LDS tree over chunks.
__global__ __launch_bounds__(256) void kan_reduce_w(const float* __restrict__ coeffs,
                                                    const float* __restrict__ hw,
                                                    float* __restrict__ w) {
    const int tid   = threadIdx.x;
    const int d4l   = tid & 15;
    const int chunk = tid >> 4;                 // 0..15, 4 neurons each
    const int d4    = blockIdx.x * 16 + d4l;

    const float4* c4 = reinterpret_cast<const float4*>(coeffs);
    float4 acc = {0.f, 0.f, 0.f, 0.f};
#pragma unroll
    for (int j = 0; j < 4; ++j) {
        const int n = chunk * 4 + j;
        const float h  = hw[n];
        const float4 c = c4[(size_t)n * D4 + d4];
        acc.x = fmaf(c.x, h, acc.x);
        acc.y = fmaf(c.y, h, acc.y);
        acc.z = fmaf(c.z, h, acc.z);
        acc.w = fmaf(c.w, h, acc.w);
    }

    __shared__ float4 part[16][16];             // [chunk][d4l]
    part[chunk][d4l] = acc;
    __syncthreads();
#pragma unroll
    for (int s = 8; s > 0; s >>= 1) {
        if (chunk < s) {
            float4 a = part[chunk][d4l], b = part[chunk + s][d4l];
            a.x += b.x; a.y += b.y; a.z += b.z; a.w += b.w;
            part[chunk][d4l] = a;
        }
        __syncthreads();
    }
    if (chunk == 0)
        reinterpret_cast<float4*>(w)[d4] = part[0][d4l];
}

// ---- Kernel B: one wave per sample; lane handles 4 input dims (float4 load).
constexpr int SPB = 16;  // samples per 256-thread block -> 1024 blocks

__global__ __launch_bounds__(256) void kan_fwd(const float* __restrict__ x,
                                               const float* __restrict__ w,
                                               float* __restrict__ out) {
    const int tid  = threadIdx.x;
    const int lane = tid & 63;
    const int wv   = tid >> 6;                  // wave 0..3
    const int b0   = blockIdx.x * SPB;

    // Lane owns dims 4*lane .. 4*lane+3; weights w[d*8 .. d*8+7] -> 8 float4s.
    const float4* w4 = reinterpret_cast<const float4*>(w) + (size_t)lane * 8;
    float4 W[4][2];
#pragma unroll
    for (int j = 0; j < 4; ++j) { W[j][0] = w4[j * 2]; W[j][1] = w4[j * 2 + 1]; }

#pragma unroll
    for (int s = wv; s < SPB; s += 4) {
        const int b = b0 + s;
        float4 xv = reinterpret_cast<const float4*>(x + (size_t)b * IN_DIM)[lane];
        float xs[4] = {xv.x, xv.y, xv.z, xv.w};
        float acc = 0.f;
#pragma unroll
        for (int j = 0; j < 4; ++j) {
            const float t  = fast_tanh(xs[j]);
            const float t2 = 2.f * t;
            const float4 wlo = W[j][0], whi = W[j][1];
            float Tm2 = 1.f, Tm1 = t, T;
            float a = fmaf(wlo.y, t, wlo.x);                                    // T0,T1
            T = t2 * Tm1 - Tm2; a = fmaf(wlo.z, T, a); Tm2 = Tm1; Tm1 = T;      // T2
            T = t2 * Tm1 - Tm2; a = fmaf(wlo.w, T, a); Tm2 = Tm1; Tm1 = T;      // T3
            T = t2 * Tm1 - Tm2; a = fmaf(whi.x, T, a); Tm2 = Tm1; Tm1 = T;      // T4
            T = t2 * Tm1 - Tm2; a = fmaf(whi.y, T, a); Tm2 = Tm1; Tm1 = T;      // T5
            T = t2 * Tm1 - Tm2; a = fmaf(whi.z, T, a); Tm2 = Tm1; Tm1 = T;      // T6
            T = t2 * Tm1 - Tm2; a = fmaf(whi.w, T, a);                          // T7
            acc += a;
        }
#pragma unroll
        for (int off = 32; off > 0; off >>= 1)
            acc += __shfl_down(acc, off, 64);
        if (lane == 0) out[b] = acc;
    }
}

extern "C" void kernel_launch(void* const* d_in, const int* in_sizes, int n_in,
                              void* d_out, int out_size, void* d_ws, size_t ws_size,
                              hipStream_t stream) {
    const float* x      = (const float*)d_in[0];   // [B, IN]
    const float* coeffs = (const float*)d_in[1];   // [N, D]
    const float* hw     = (const float*)d_in[2];   // [N]
    float* out = (float*)d_out;                    // [B]
    float* w   = (float*)d_ws;                     // 2048 floats scratch

    kan_reduce_w<<<D4 / 16, 256, 0, stream>>>(coeffs, hw, w);
    kan_fwd<<<B_SAMPLES / SPB, 256, 0, stream>>>(x, w, out);
}